// Round 3
// baseline (25.407 us; speedup 1.0000x reference)
//
#include <hip/hip_runtime.h>
#include <hip/hip_bf16.h>

// Fully-fused quantum photonic classifier, subset-factored Ryser.
// One block per sample (256 blocks x 512 threads). Per circuit we precompute
// v[s][m] = sum_{c in s} B[m][c] (31 subsets x 10 modes) in LDS; each 5x5
// permanent is then 31 steps of {5 ds_read_b64 + 4 cmul + signed add}.
// Row multisets are 4-bit-packed into LDS u32 once per block.

__device__ __forceinline__ float2 cmul(float2 a, float2 b) {
    return make_float2(fmaf(a.x, b.x, -a.y * b.y), fmaf(a.x, b.y, a.y * b.x));
}

template<int S>
__device__ __forceinline__ void pstep(const float2 (&v)[32][10], const int (&m)[5], float2& pm) {
    float2 p = v[S][m[0]];
    p = cmul(p, v[S][m[1]]);
    p = cmul(p, v[S][m[2]]);
    p = cmul(p, v[S][m[3]]);
    p = cmul(p, v[S][m[4]]);
    constexpr int pc = ((S >> 0) & 1) + ((S >> 1) & 1) + ((S >> 2) & 1) + ((S >> 3) & 1) + ((S >> 4) & 1);
    if constexpr (((5 - pc) & 1) != 0) { pm.x -= p.x; pm.y -= p.y; }
    else                               { pm.x += p.x; pm.y += p.y; }
}

template<int S>
__device__ __forceinline__ void pall(const float2 (&v)[32][10], const int (&m)[5], float2& pm) {
    pstep<S>(v, m, pm);
    if constexpr (S < 31) pall<S + 1>(v, m, pm);
}

// |perm|^2 of the 5x5 matrix whose rows are modes packed 4-bit in `packed`.
__device__ __forceinline__ float perm5v_sq(const float2 (&v)[32][10], unsigned packed) {
    int m[5];
#pragma unroll
    for (int r = 0; r < 5; ++r) m[r] = (packed >> (4 * r)) & 15u;
    float2 pm = make_float2(0.f, 0.f);
    pall<1>(v, m, pm);
    return fmaf(pm.x, pm.x, pm.y * pm.y);
}

__global__ __launch_bounds__(512) void k_fused(
    const float* __restrict__ x, const float* __restrict__ Wd, const float* __restrict__ bd,
    const float* __restrict__ U1L, const float* __restrict__ U1R,
    const float* __restrict__ UfL, const float* __restrict__ UfR,
    const float* __restrict__ Wout, const float* __restrict__ bout,
    const float* __restrict__ mask1, const float* __restrict__ norm2,
    const int* __restrict__ rows1, const int* __restrict__ rows2,
    float* __restrict__ out)
{
    const int n    = blockIdx.x;
    const int tid  = threadIdx.x;
    const int lane = tid & 63;
    const int wid  = tid >> 6;   // 8 waves

    __shared__ float2   Bsh[50];        // B1 then B2 (10 modes x 5 cols)
    __shared__ float2   vsh[32][10];    // subset-factored row sums
    __shared__ unsigned pr1[252];       // packed rows1
    __shared__ unsigned pr2[2002];      // packed rows2
    __shared__ float    p1s[256];
    __shared__ float2   Dsh[10];
    __shared__ float    sred[10][8];
    __shared__ float    epart[32][10];
    __shared__ float    tred[4];
    __shared__ float    fred[8][2];

    // ---- pack row multisets into LDS (4 bits per mode) ------------------
    for (int p = tid; p < 2002; p += 512) {
        const int* r = rows2 + p * 5;
        pr2[p] = (unsigned)r[0] | ((unsigned)r[1] << 4) | ((unsigned)r[2] << 8)
               | ((unsigned)r[3] << 12) | ((unsigned)r[4] << 16);
    }
    if (tid < 252) {
        const int* r = rows1 + tid * 5;
        pr1[tid] = (unsigned)r[0] | ((unsigned)r[1] << 4) | ((unsigned)r[2] << 8)
                 | ((unsigned)r[3] << 12) | ((unsigned)r[4] << 16);
    }

    // ---- phase 1: h = x[n] @ Wd^T + bd -> D1 = exp(i h/pi) --------------
    float acc[10];
#pragma unroll
    for (int j = 0; j < 10; ++j) acc[j] = 0.f;
    const float* xr = x + n * 784;
    for (int k = tid; k < 784; k += 512) {
        float xv = xr[k];
#pragma unroll
        for (int j = 0; j < 10; ++j) acc[j] = fmaf(xv, Wd[j * 784 + k], acc[j]);
    }
#pragma unroll
    for (int off = 32; off > 0; off >>= 1)
#pragma unroll
        for (int j = 0; j < 10; ++j) acc[j] += __shfl_xor(acc[j], off, 64);
    if (lane == 0)
#pragma unroll
        for (int j = 0; j < 10; ++j) sred[j][wid] = acc[j];
    __syncthreads();
    if (tid < 10) {
        float h = bd[tid];
#pragma unroll
        for (int w = 0; w < 8; ++w) h += sred[tid][w];
        float s, c;
        sincosf(h * 0.31830988618379067154f, &s, &c);   // h / pi
        Dsh[tid] = make_float2(c, s);
    }
    __syncthreads();
    // B1 = U1L diag(D1) U1R[:, even]
    if (tid < 50) {
        const int i = tid / 5, k = 2 * (tid % 5);
        float2 a = make_float2(0.f, 0.f);
#pragma unroll
        for (int j = 0; j < 10; ++j) {
            float2 ul = make_float2(U1L[(i * 10 + j) * 2], U1L[(i * 10 + j) * 2 + 1]);
            float2 ur = make_float2(U1R[(j * 10 + k) * 2], U1R[(j * 10 + k) * 2 + 1]);
            float2 t = cmul(cmul(ul, Dsh[j]), ur);
            a.x += t.x; a.y += t.y;
        }
        Bsh[tid] = a;
    }
    __syncthreads();
    // v1[s][m] = sum_{c in s} B1[m][c]
    if (tid < 310) {
        const int s = (tid / 10) + 1, m = tid - (tid / 10) * 10;
        float2 a = make_float2(0.f, 0.f);
#pragma unroll
        for (int c = 0; c < 5; ++c) {
            float b = (float)((s >> c) & 1);
            a.x = fmaf(b, Bsh[m * 5 + c].x, a.x);
            a.y = fmaf(b, Bsh[m * 5 + c].y, a.y);
        }
        vsh[s][m] = a;
    }
    __syncthreads();

    // ---- phase 2: circuit-1 permanents (252) -> e1 -> D2 -> B2 ----------
    float p1 = 0.f;
    if (tid < 252) p1 = perm5v_sq(vsh, pr1[tid]);
    if (tid < 256) p1s[tid] = p1;
    __syncthreads();
    if (tid < 256) {
        float vv = p1s[tid];
#pragma unroll
        for (int off = 32; off > 0; off >>= 1) vv += __shfl_xor(vv, off, 64);
        if (lane == 0) tred[wid] = vv;
    }
    if (tid < 320) {
        const int c = tid / 10, j = tid - c * 10;
        float s = 0.f;
        const int p0 = c * 8, p1e = (p0 + 8 < 252) ? p0 + 8 : 252;
        for (int p = p0; p < p1e; ++p) s = fmaf(p1s[p], mask1[p * 10 + j], s);
        epart[c][j] = s;
    }
    __syncthreads();
    if (tid < 10) {
        const float total = tred[0] + tred[1] + tred[2] + tred[3];
        float e = 0.f;
#pragma unroll
        for (int c = 0; c < 32; ++c) e += epart[c][tid];
        e /= total;
        float s, cc;
        sincosf(e, &s, &cc);
        Dsh[tid] = make_float2(cc, s);
    }
    __syncthreads();
    if (tid < 50) {
        const int i = tid / 5, k = 2 * (tid % 5);
        float2 a = make_float2(0.f, 0.f);
#pragma unroll
        for (int j = 0; j < 10; ++j) {
            float2 ul = make_float2(UfL[(i * 10 + j) * 2], UfL[(i * 10 + j) * 2 + 1]);
            float2 ur = make_float2(UfR[(j * 10 + k) * 2], UfR[(j * 10 + k) * 2 + 1]);
            float2 t = cmul(cmul(ul, Dsh[j]), ur);
            a.x += t.x; a.y += t.y;
        }
        Bsh[tid] = a;   // overwrite with B2 (all B1/v1 consumers done)
    }
    __syncthreads();
    // v2[s][m] from B2
    if (tid < 310) {
        const int s = (tid / 10) + 1, m = tid - (tid / 10) * 10;
        float2 a = make_float2(0.f, 0.f);
#pragma unroll
        for (int c = 0; c < 5; ++c) {
            float b = (float)((s >> c) & 1);
            a.x = fmaf(b, Bsh[m * 5 + c].x, a.x);
            a.y = fmaf(b, Bsh[m * 5 + c].y, a.y);
        }
        vsh[s][m] = a;
    }
    __syncthreads();

    // ---- phase 3: circuit-2 permanents (2002) + dot with W_out ----------
    float f0 = 0.f, f1 = 0.f;
    for (int p = tid; p < 2002; p += 512) {
        float pf = perm5v_sq(vsh, pr2[p]) * norm2[p];
        f0 = fmaf(pf, Wout[p], f0);
        f1 = fmaf(pf, Wout[2002 + p], f1);
    }
#pragma unroll
    for (int off = 32; off > 0; off >>= 1) {
        f0 += __shfl_xor(f0, off, 64);
        f1 += __shfl_xor(f1, off, 64);
    }
    if (lane == 0) { fred[wid][0] = f0; fred[wid][1] = f1; }
    __syncthreads();
    if (tid < 2) {
        float a = bout[tid];
#pragma unroll
        for (int w = 0; w < 8; ++w) a += fred[w][tid];
        out[n * 2 + tid] = a;
    }
}

extern "C" void kernel_launch(void* const* d_in, const int* in_sizes, int n_in,
                              void* d_out, int out_size, void* d_ws, size_t ws_size,
                              hipStream_t stream) {
    const float* x     = (const float*)d_in[0];
    const float* Wd    = (const float*)d_in[1];
    const float* bd    = (const float*)d_in[2];
    const float* U1L   = (const float*)d_in[3];
    const float* U1R   = (const float*)d_in[4];
    const float* UfL   = (const float*)d_in[5];
    const float* UfR   = (const float*)d_in[6];
    const float* Wout  = (const float*)d_in[7];
    const float* bout  = (const float*)d_in[8];
    const float* mask1 = (const float*)d_in[9];
    const float* norm2 = (const float*)d_in[10];
    const int*   rows1 = (const int*)d_in[11];
    const int*   rows2 = (const int*)d_in[12];
    float* out = (float*)d_out;

    hipLaunchKernelGGL(k_fused, dim3(256), dim3(512), 0, stream,
                       x, Wd, bd, U1L, U1R, UfL, UfR, Wout, bout,
                       mask1, norm2, rows1, rows2, out);
}

// Round 4
// 19.345 us; speedup vs baseline: 1.3134x; 1.3134x over previous
//
#include <hip/hip_runtime.h>
#include <hip/hip_bf16.h>

// Fully-fused quantum photonic classifier.
// Permanent core: Glynn/BBF formula (16 Gray-coded sign vectors, not Ryser's
// 31 subsets) computed 2-permanents-per-thread via packed fp32 VOP3P ops
// (v_pk_fma_f32 etc.), re/im planes packed across VGPR pairs.
// One block per sample: 256 blocks x 512 threads, everything in regs/LDS.

typedef float v2f __attribute__((ext_vector_type(2)));

__device__ __forceinline__ v2f pk_mul(v2f a, v2f b) {
    v2f d;
    asm("v_pk_mul_f32 %0, %1, %2" : "=v"(d) : "v"(a), "v"(b));
    return d;
}
__device__ __forceinline__ v2f pk_fma(v2f a, v2f b, v2f c) {
    v2f d;
    asm("v_pk_fma_f32 %0, %1, %2, %3" : "=v"(d) : "v"(a), "v"(b), "v"(c));
    return d;
}
__device__ __forceinline__ v2f pk_add(v2f a, v2f b) {
    v2f d;
    asm("v_pk_add_f32 %0, %1, %2" : "=v"(d) : "v"(a), "v"(b));
    return d;
}

// scalar complex mul (one complex number in a v2f as (re,im))
__device__ __forceinline__ v2f cxmul(v2f a, v2f b) {
    v2f r;
    r.x = fmaf(a.x, b.x, -a.y * b.y);
    r.y = fmaf(a.x, b.y, a.y * b.x);
    return r;
}

// product over 5 packed row-sums (two independent complex chains)
__device__ __forceinline__ void prod5(const v2f (&rre)[5], const v2f (&rim)[5],
                                      v2f& zr, v2f& zi, v2f cm1) {
    v2f ar = rre[0], ai = rim[0];
#pragma unroll
    for (int r = 1; r < 5; ++r) {
        v2f t = pk_mul(ai, rim[r]);
        t = pk_mul(t, cm1);                 // -ai*bi
        v2f nr = pk_fma(ar, rre[r], t);     // ar*br - ai*bi
        v2f u = pk_mul(ar, rim[r]);
        v2f ni = pk_fma(ai, rre[r], u);     // ai*br + ar*bi
        ar = nr; ai = ni;
    }
    zr = ar; zi = ai;
}

template<int K>
__device__ __forceinline__ void glynn_rest(const v2f (&Are)[5][5], const v2f (&Aim)[5][5],
    v2f (&rre)[5], v2f (&rim)[5], v2f& pre, v2f& pim,
    v2f cp1, v2f cm1, v2f cp2, v2f cm2)
{
    constexpr unsigned g    = (unsigned)K ^ ((unsigned)K >> 1);
    constexpr unsigned og   = (unsigned)(K - 1) ^ ((unsigned)(K - 1) >> 1);
    constexpr unsigned diff = g ^ og;
    constexpr int b = (diff & 1u) ? 0 : (diff & 2u) ? 1 : (diff & 4u) ? 2 : 3;
    constexpr int j = b + 1;                 // columns 1..4 carry varying signs
    constexpr bool sub = (g & diff) != 0u;   // bit ->1 means delta ->-1: subtract 2A
    const v2f c2 = sub ? cm2 : cp2;
#pragma unroll
    for (int r = 0; r < 5; ++r) {
        rre[r] = pk_fma(Are[r][j], c2, rre[r]);
        rim[r] = pk_fma(Aim[r][j], c2, rim[r]);
    }
    v2f zr, zi;
    prod5(rre, rim, zr, zi, cm1);
    constexpr int pc = ((g >> 0) & 1) + ((g >> 1) & 1) + ((g >> 2) & 1) + ((g >> 3) & 1);
    const v2f cs = (pc & 1) ? cm1 : cp1;
    pre = pk_fma(zr, cs, pre);
    pim = pk_fma(zi, cs, pim);
    if constexpr (K < 15) glynn_rest<K + 1>(Are, Aim, rre, rim, pre, pim, cp1, cm1, cp2, cm2);
}

// |perm|^2 for TWO 5x5 complex matrices (rows 4-bit packed in m0/m1),
// columns taken from Bsh (10 modes x 5 cols, AoS complex).
__device__ __forceinline__ void glynn_pair_sq(const v2f* __restrict__ Bsh,
    unsigned m0, unsigned m1, v2f cp1, v2f cm1, v2f cp2, v2f cm2,
    float& sq0, float& sq1)
{
    v2f Are[5][5], Aim[5][5];
#pragma unroll
    for (int r = 0; r < 5; ++r) {
        const v2f* b0 = Bsh + ((m0 >> (4 * r)) & 15u) * 5;
        const v2f* b1 = Bsh + ((m1 >> (4 * r)) & 15u) * 5;
#pragma unroll
        for (int c = 0; c < 5; ++c) {
            const v2f e0 = b0[c];
            const v2f e1 = b1[c];
            v2f ar; ar.x = e0.x; ar.y = e1.x;
            v2f ai; ai.x = e0.y; ai.y = e1.y;
            Are[r][c] = ar; Aim[r][c] = ai;
        }
    }
    v2f rre[5], rim[5];
#pragma unroll
    for (int r = 0; r < 5; ++r) {
        rre[r] = pk_add(pk_add(pk_add(Are[r][0], Are[r][1]), pk_add(Are[r][2], Are[r][3])), Are[r][4]);
        rim[r] = pk_add(pk_add(pk_add(Aim[r][0], Aim[r][1]), pk_add(Aim[r][2], Aim[r][3])), Aim[r][4]);
    }
    v2f pre, pim;
    prod5(rre, rim, pre, pim, cm1);          // g = 0 term, sign +
    glynn_rest<1>(Are, Aim, rre, rim, pre, pim, cp1, cm1, cp2, cm2);
    // perm = pm / 16  ->  |perm|^2 = (pre^2+pim^2) / 256
    sq0 = fmaf(pre.x, pre.x, pim.x * pim.x);
    sq1 = fmaf(pre.y, pre.y, pim.y * pim.y);
}

__device__ __forceinline__ unsigned pack_rows(const int* __restrict__ r) {
    return (unsigned)r[0] | ((unsigned)r[1] << 4) | ((unsigned)r[2] << 8)
         | ((unsigned)r[3] << 12) | ((unsigned)r[4] << 16);
}

__global__ __launch_bounds__(512) void k_fused(
    const float* __restrict__ x, const float* __restrict__ Wd, const float* __restrict__ bd,
    const float* __restrict__ U1L, const float* __restrict__ U1R,
    const float* __restrict__ UfL, const float* __restrict__ UfR,
    const float* __restrict__ Wout, const float* __restrict__ bout,
    const float* __restrict__ mask1, const float* __restrict__ norm2,
    const int* __restrict__ rows1, const int* __restrict__ rows2,
    float* __restrict__ out)
{
    const int n    = blockIdx.x;
    const int tid  = threadIdx.x;
    const int lane = tid & 63;
    const int wid  = tid >> 6;   // 8 waves

    __shared__ v2f   Bsh[50];        // B1 then B2 (10 modes x 5 cols)
    __shared__ float p1s[256];
    __shared__ v2f   Dsh[10];
    __shared__ float sred[10][8];
    __shared__ float epart[32][10];
    __shared__ float tred[4];
    __shared__ float fred[8][2];

    v2f cp1; cp1.x = 1.f;  cp1.y = 1.f;
    v2f cm1; cm1.x = -1.f; cm1.y = -1.f;
    v2f cp2; cp2.x = 2.f;  cp2.y = 2.f;
    v2f cm2; cm2.x = -2.f; cm2.y = -2.f;

    // ---- phase 1: h = x[n] @ Wd^T + bd -> D1 = exp(i h/pi) --------------
    float acc[10];
#pragma unroll
    for (int j = 0; j < 10; ++j) acc[j] = 0.f;
    const float* xr = x + n * 784;
    for (int k = tid; k < 784; k += 512) {
        float xv = xr[k];
#pragma unroll
        for (int j = 0; j < 10; ++j) acc[j] = fmaf(xv, Wd[j * 784 + k], acc[j]);
    }
#pragma unroll
    for (int off = 32; off > 0; off >>= 1)
#pragma unroll
        for (int j = 0; j < 10; ++j) acc[j] += __shfl_xor(acc[j], off, 64);
    if (lane == 0)
#pragma unroll
        for (int j = 0; j < 10; ++j) sred[j][wid] = acc[j];
    __syncthreads();
    if (tid < 10) {
        float h = bd[tid];
#pragma unroll
        for (int w = 0; w < 8; ++w) h += sred[tid][w];
        float s, c;
        sincosf(h * 0.31830988618379067154f, &s, &c);   // h / pi
        v2f d; d.x = c; d.y = s;
        Dsh[tid] = d;
    }
    __syncthreads();
    // B1 = U1L diag(D1) U1R[:, even]
    if (tid < 50) {
        const int i = tid / 5, k = 2 * (tid % 5);
        v2f a; a.x = 0.f; a.y = 0.f;
#pragma unroll
        for (int j = 0; j < 10; ++j) {
            v2f ul; ul.x = U1L[(i * 10 + j) * 2]; ul.y = U1L[(i * 10 + j) * 2 + 1];
            v2f ur; ur.x = U1R[(j * 10 + k) * 2]; ur.y = U1R[(j * 10 + k) * 2 + 1];
            v2f t = cxmul(cxmul(ul, Dsh[j]), ur);
            a.x += t.x; a.y += t.y;
        }
        Bsh[tid] = a;
    }
    __syncthreads();

    // ---- phase 2: circuit-1 permanents (252 = 126 pairs) -> e1 -> D2 -> B2
    // 1/256 scale cancels in the p1/total normalization -> skip it here.
    if (tid < 126) {
        unsigned m0 = pack_rows(rows1 + (2 * tid) * 5);
        unsigned m1 = pack_rows(rows1 + (2 * tid + 1) * 5);
        float sq0, sq1;
        glynn_pair_sq(Bsh, m0, m1, cp1, cm1, cp2, cm2, sq0, sq1);
        p1s[2 * tid]     = sq0;
        p1s[2 * tid + 1] = sq1;
    } else if (tid < 128) {
        p1s[2 * tid] = 0.f;
        p1s[2 * tid + 1] = 0.f;
    }
    __syncthreads();
    if (tid < 256) {
        float vv = p1s[tid];
#pragma unroll
        for (int off = 32; off > 0; off >>= 1) vv += __shfl_xor(vv, off, 64);
        if (lane == 0) tred[wid] = vv;
    }
    if (tid < 320) {
        const int c = tid / 10, j = tid - c * 10;
        float s = 0.f;
        const int p0 = c * 8, p1e = (p0 + 8 < 252) ? p0 + 8 : 252;
        for (int p = p0; p < p1e; ++p) s = fmaf(p1s[p], mask1[p * 10 + j], s);
        epart[c][j] = s;
    }
    __syncthreads();
    if (tid < 10) {
        const float total = tred[0] + tred[1] + tred[2] + tred[3];
        float e = 0.f;
#pragma unroll
        for (int c = 0; c < 32; ++c) e += epart[c][tid];
        e /= total;
        float s, cc;
        sincosf(e, &s, &cc);
        v2f d; d.x = cc; d.y = s;
        Dsh[tid] = d;
    }
    __syncthreads();
    if (tid < 50) {
        const int i = tid / 5, k = 2 * (tid % 5);
        v2f a; a.x = 0.f; a.y = 0.f;
#pragma unroll
        for (int j = 0; j < 10; ++j) {
            v2f ul; ul.x = UfL[(i * 10 + j) * 2]; ul.y = UfL[(i * 10 + j) * 2 + 1];
            v2f ur; ur.x = UfR[(j * 10 + k) * 2]; ur.y = UfR[(j * 10 + k) * 2 + 1];
            v2f t = cxmul(cxmul(ul, Dsh[j]), ur);
            a.x += t.x; a.y += t.y;
        }
        Bsh[tid] = a;   // overwrite with B2 (all B1 consumers done)
    }
    __syncthreads();

    // ---- phase 3: circuit-2 permanents (2002 = 1001 pairs) + W_out dot --
    float f0 = 0.f, f1 = 0.f;
#pragma unroll 1
    for (int q = tid; q < 1001; q += 512) {
        const int p0 = 2 * q, p1 = 2 * q + 1;
        unsigned m0 = pack_rows(rows2 + p0 * 5);
        unsigned m1 = pack_rows(rows2 + p1 * 5);
        float sq0, sq1;
        glynn_pair_sq(Bsh, m0, m1, cp1, cm1, cp2, cm2, sq0, sq1);
        const float pf0 = sq0 * norm2[p0] * 0.00390625f;   // 1/256 Glynn scale
        const float pf1 = sq1 * norm2[p1] * 0.00390625f;
        f0 = fmaf(pf0, Wout[p0], f0);
        f0 = fmaf(pf1, Wout[p1], f0);
        f1 = fmaf(pf0, Wout[2002 + p0], f1);
        f1 = fmaf(pf1, Wout[2002 + p1], f1);
    }
#pragma unroll
    for (int off = 32; off > 0; off >>= 1) {
        f0 += __shfl_xor(f0, off, 64);
        f1 += __shfl_xor(f1, off, 64);
    }
    if (lane == 0) { fred[wid][0] = f0; fred[wid][1] = f1; }
    __syncthreads();
    if (tid < 2) {
        float a = bout[tid];
#pragma unroll
        for (int w = 0; w < 8; ++w) a += fred[w][tid];
        out[n * 2 + tid] = a;
    }
}

extern "C" void kernel_launch(void* const* d_in, const int* in_sizes, int n_in,
                              void* d_out, int out_size, void* d_ws, size_t ws_size,
                              hipStream_t stream) {
    const float* x     = (const float*)d_in[0];
    const float* Wd    = (const float*)d_in[1];
    const float* bd    = (const float*)d_in[2];
    const float* U1L   = (const float*)d_in[3];
    const float* U1R   = (const float*)d_in[4];
    const float* UfL   = (const float*)d_in[5];
    const float* UfR   = (const float*)d_in[6];
    const float* Wout  = (const float*)d_in[7];
    const float* bout  = (const float*)d_in[8];
    const float* mask1 = (const float*)d_in[9];
    const float* norm2 = (const float*)d_in[10];
    const int*   rows1 = (const int*)d_in[11];
    const int*   rows2 = (const int*)d_in[12];
    float* out = (float*)d_out;

    hipLaunchKernelGGL(k_fused, dim3(256), dim3(512), 0, stream,
                       x, Wd, bd, U1L, U1R, UfL, UfR, Wout, bout,
                       mask1, norm2, rows1, rows2, out);
}